// Round 1
// baseline (55.934 us; speedup 1.0000x reference)
//
#include <hip/hip_runtime.h>
#include <math.h>

#define BS 4
#define CH 256
#define XD 1024
#define N 128
#define NP 8128
#define TWO_PI_F 6.283185307179586f

// ---------------------------------------------------------------------------
// K1: per-batch pairwise squared distances over the channel axis.
//   xr2[b,i,j] = sum_c (x[b,c,dims[i]] - x[b,c,dims[j]])^2
//   vr2[b,i,j] = same with a (vv = a*DT, DT=1)
// grid (8,8,4): 16x16 output tile per block, 256 threads.
// ---------------------------------------------------------------------------
__global__ __launch_bounds__(256) void k1_pairdist(
    const float* __restrict__ x, const float* __restrict__ a,
    const int* __restrict__ dims,
    float* __restrict__ xr2, float* __restrict__ vr2) {
  int ti = blockIdx.x, tj = blockIdx.y, b = blockIdx.z;
  int t = threadIdx.x;
  __shared__ float sXi[CH][16];
  __shared__ float sXj[CH][16];
  __shared__ float sAi[CH][16];
  __shared__ float sAj[CH][16];

  int lane16 = t & 15, grp = t >> 4;
  int di = dims[ti * 16 + lane16];
  int dj = dims[tj * 16 + lane16];
  const float* xb = x + (size_t)b * CH * XD;
  const float* ab = a + (size_t)b * CH * XD;
  for (int c0 = 0; c0 < CH; c0 += 16) {
    int c = c0 + grp;
    sXi[c][lane16] = xb[c * XD + di];
    sXj[c][lane16] = xb[c * XD + dj];
    sAi[c][lane16] = ab[c * XD + di];
    sAj[c][lane16] = ab[c * XD + dj];
  }
  __syncthreads();

  int ii = t >> 4, jj = t & 15;  // write: consecutive t -> consecutive j (coalesced)
  float accx = 0.f, accv = 0.f;
#pragma unroll 4
  for (int c = 0; c < CH; ++c) {
    float dx = sXi[c][ii] - sXj[c][jj];
    accx += dx * dx;
    float dv = sAi[c][ii] - sAj[c][jj];
    accv += dv * dv;
  }
  int i = ti * 16 + ii, j = tj * 16 + jj;
  xr2[((size_t)b * N + i) * N + j] = accx;
  vr2[((size_t)b * N + i) * N + j] = accv;
}

// ---------------------------------------------------------------------------
// K2: per-batch v_r max, then collision mask bits (column-major bitmask).
//   mask[b,i,j] = (v_r/v_r_max * exp(-x_r)) > 0.5
//   colmask[b][j][w] bit (i&31) for i in [32w, 32w+32)
// grid (4), 256 threads.
// ---------------------------------------------------------------------------
__global__ __launch_bounds__(256) void k2_mask(
    const float* __restrict__ xr2, const float* __restrict__ vr2,
    unsigned* __restrict__ colmask) {
  int b = blockIdx.x;
  int t = threadIdx.x;
  __shared__ float red[256];
  __shared__ unsigned m[N * 4];
  for (int k = t; k < N * 4; k += 256) m[k] = 0u;

  const float* vb = vr2 + (size_t)b * N * N;
  const float* xb = xr2 + (size_t)b * N * N;
  float mx = 0.f;
  for (int e = t; e < N * N; e += 256) mx = fmaxf(mx, vb[e]);
  red[t] = mx;
  __syncthreads();
  for (int s = 128; s > 0; s >>= 1) {
    if (t < s) red[t] = fmaxf(red[t], red[t + s]);
    __syncthreads();
  }
  float vrmax = sqrtf(red[0]);
  float inv = vrmax > 0.f ? 1.f / vrmax : 0.f;  // vrmax==0 -> mask all false (matches nan>0.5)

  for (int e = t; e < N * N; e += 256) {
    int i = e >> 7, j = e & 127;
    float vr = sqrtf(vb[e]);
    float ux = expf(-sqrtf(xb[e]));
    if (vr * inv * ux > 0.5f) {
      atomicOr(&m[j * 4 + (i >> 5)], 1u << (i & 31));
    }
  }
  __syncthreads();
  for (int k = t; k < N * 4; k += 256) colmask[(size_t)b * N * 4 + k] = m[k];
}

// ---------------------------------------------------------------------------
// K3: per-(b,c) update, one block each (1024 blocks, 256 threads).
//   passthrough: out[k] = x[k]+a[k] for k not in dims
//   kinetic dims j: closed-form v_new/x_new with masked sums (usually empty)
// ---------------------------------------------------------------------------
__global__ __launch_bounds__(256) void k3_update(
    const float* __restrict__ x, const float* __restrict__ a,
    const float* __restrict__ ru, const int* __restrict__ dims,
    const float* __restrict__ vr2, const unsigned* __restrict__ colmask,
    float* __restrict__ out) {
  int bc = blockIdx.x;  // b*256 + c
  int b = bc >> 8;
  int t = threadIdx.x;
  __shared__ float xx[N];
  __shared__ float vv[N];
  __shared__ int dsh[N];
  __shared__ unsigned inset[XD / 32];
  if (t < XD / 32) inset[t] = 0u;
  __syncthreads();

  const float* xrow = x + (size_t)bc * XD;
  const float* arow = a + (size_t)bc * XD;
  float* orow = out + (size_t)bc * XD;

  if (t < N) {
    int d = dims[t];
    dsh[t] = d;
    xx[t] = xrow[d];
    vv[t] = arow[d];  // vv = a * DT, DT = 1
    atomicOr(&inset[d >> 5], 1u << (d & 31));
  }
  __syncthreads();

  // passthrough for non-dims positions
  for (int k = t; k < XD; k += 256) {
    if (!((inset[k >> 5] >> (k & 31)) & 1u)) orow[k] = xrow[k] + arow[k];
  }

  if (t < N) {
    int j = t;
    const unsigned* cm = colmask + ((size_t)b * N + j) * 4;
    unsigned mw0 = cm[0], mw1 = cm[1], mw2 = cm[2], mw3 = cm[3];
    float S = 0.f, sumV = 0.f, sumX = 0.f, R = 0.f;
    if (mw0 | mw1 | mw2 | mw3) {
      const float* vrb = vr2 + (size_t)b * N * N;
      const float* rub = ru + (size_t)bc * NP;
      unsigned mw[4] = {mw0, mw1, mw2, mw3};
      for (int w = 0; w < 4; ++w) {
        unsigned bits = mw[w];
        while (bits) {
          int i = (w << 5) + __ffs(bits) - 1;
          bits &= bits - 1;
          S += 1.f;
          sumV += vv[i];
          sumX += xx[i];
          float vr = sqrtf(vrb[i * N + j]);
          int p;
          float sgn;
          if (i < j) {
            p = i * N - ((i * (i + 1)) >> 1) + (j - i - 1);
            sgn = 1.f;
          } else {
            p = j * N - ((j * (j + 1)) >> 1) + (i - j - 1);
            sgn = -1.f;
          }
          R += sgn * TWO_PI_F * vr * rub[p];
        }
      }
    }
    float vj = vv[j];
    float v_new = vj + 0.5f * S * vj - 0.5f * sumV + R;
    float Dd = S + 1.f;
    float T = xx[j] + sumX;
    float x_new = 0.5f * xx[j] + 0.5f * T / Dd + 0.5f * v_new;
    orow[dsh[j]] = x_new;
  }
}

extern "C" void kernel_launch(void* const* d_in, const int* in_sizes, int n_in,
                              void* d_out, int out_size, void* d_ws, size_t ws_size,
                              hipStream_t stream) {
  const float* x = (const float*)d_in[0];
  // d_in[1] = v : unused by the reference computation
  const float* a = (const float*)d_in[2];
  const float* ru = (const float*)d_in[3];
  const int* dims = (const int*)d_in[4];
  float* out = (float*)d_out;

  float* xr2 = (float*)d_ws;                     // BS*N*N f32
  float* vr2 = xr2 + (size_t)BS * N * N;         // BS*N*N f32
  unsigned* colmask = (unsigned*)(vr2 + (size_t)BS * N * N);  // BS*N*4 u32

  k1_pairdist<<<dim3(8, 8, BS), 256, 0, stream>>>(x, a, dims, xr2, vr2);
  k2_mask<<<BS, 256, 0, stream>>>(xr2, vr2, colmask);
  k3_update<<<BS * CH, 256, 0, stream>>>(x, a, ru, dims, vr2, colmask, out);
}

// Round 2
// 22.508 us; speedup vs baseline: 2.4851x; 2.4851x over previous
//
#include <hip/hip_runtime.h>
#include <math.h>

#define BS 4
#define CH 256
#define XD 1024
#define N 128
#define NP 8128
#define TWO_PI_F 6.283185307179586f

// ---------------------------------------------------------------------------
// K1: per-batch pairwise squared distances over the channel axis, plus a
// per-block partial max of vr2 (for the v_r_max reduction).
//   xr2[b,i,j] = sum_c (x[b,c,dims[i]] - x[b,c,dims[j]])^2
//   vr2[b,i,j] = same with a (vv = a*DT, DT=1)
//   pmax[b*64 + tj*8 + ti] = max over the 16x16 tile of vr2
// grid (8,8,4): 16x16 output tile per block, 256 threads.
// ---------------------------------------------------------------------------
__global__ __launch_bounds__(256) void k1_pairdist(
    const float* __restrict__ x, const float* __restrict__ a,
    const int* __restrict__ dims,
    float* __restrict__ xr2, float* __restrict__ vr2,
    float* __restrict__ pmax) {
  int ti = blockIdx.x, tj = blockIdx.y, b = blockIdx.z;
  int t = threadIdx.x;
  __shared__ float sXi[CH][16];
  __shared__ float sXj[CH][16];
  __shared__ float sAi[CH][16];
  __shared__ float sAj[CH][16];
  __shared__ float red[256];

  int lane16 = t & 15, grp = t >> 4;
  int di = dims[ti * 16 + lane16];
  int dj = dims[tj * 16 + lane16];
  const float* xb = x + (size_t)b * CH * XD;
  const float* ab = a + (size_t)b * CH * XD;
  for (int c0 = 0; c0 < CH; c0 += 16) {
    int c = c0 + grp;
    sXi[c][lane16] = xb[c * XD + di];
    sXj[c][lane16] = xb[c * XD + dj];
    sAi[c][lane16] = ab[c * XD + di];
    sAj[c][lane16] = ab[c * XD + dj];
  }
  __syncthreads();

  int ii = t >> 4, jj = t & 15;  // write: consecutive t -> consecutive j (coalesced)
  float accx = 0.f, accv = 0.f;
#pragma unroll 4
  for (int c = 0; c < CH; ++c) {
    float dx = sXi[c][ii] - sXj[c][jj];
    accx += dx * dx;
    float dv = sAi[c][ii] - sAj[c][jj];
    accv += dv * dv;
  }
  int i = ti * 16 + ii, j = tj * 16 + jj;
  xr2[((size_t)b * N + i) * N + j] = accx;
  vr2[((size_t)b * N + i) * N + j] = accv;

  // partial max of vr2 over this block's 256 elements
  red[t] = accv;
  __syncthreads();
  for (int s = 128; s > 0; s >>= 1) {
    if (t < s) red[t] = fmaxf(red[t], red[t + s]);
    __syncthreads();
  }
  if (t == 0) pmax[(b << 6) + tj * 8 + ti] = red[0];
}

// ---------------------------------------------------------------------------
// K2: finish the max reduction (64 partials per batch), then collision mask
// bits in a column-major bitmask.
//   mask[b,i,j] = (v_r/v_r_max * exp(-x_r)) > 0.5
//   colmask[b][j][w] bit (i&31) for i in [32w, 32w+32)
// grid (8, 4): block handles 16 columns of one batch, 256 threads.
// ---------------------------------------------------------------------------
__global__ __launch_bounds__(256) void k2_mask(
    const float* __restrict__ xr2, const float* __restrict__ vr2,
    const float* __restrict__ pmax, unsigned* __restrict__ colmask) {
  int g = blockIdx.x;  // column group: j in [16g, 16g+16)
  int b = blockIdx.y;
  int t = threadIdx.x;
  __shared__ float red[64];
  __shared__ unsigned m[16 * 4];
  if (t < 64) red[t] = pmax[(b << 6) + t];
  if (t < 64) m[t] = 0u;
  __syncthreads();
  float mx = 0.f;
#pragma unroll
  for (int k = 0; k < 64; ++k) mx = fmaxf(mx, red[k]);  // LDS broadcast, cheap
  float vrmax = sqrtf(mx);
  float inv = vrmax > 0.f ? 1.f / vrmax : 0.f;  // vrmax==0 -> all-false (matches nan>0.5)

  const float* vb = vr2 + (size_t)b * N * N;
  const float* xb = xr2 + (size_t)b * N * N;
  int jl = t & 15;            // local column
  int j = (g << 4) + jl;
  int i0 = t >> 4;            // 0..15
  unsigned acc[4] = {0u, 0u, 0u, 0u};
#pragma unroll
  for (int pass = 0; pass < 8; ++pass) {
    int i = (pass << 4) + i0;
    float vr = sqrtf(vb[i * N + j]);
    float ux = expf(-sqrtf(xb[i * N + j]));
    if (vr * inv * ux > 0.5f) acc[i >> 5] |= 1u << (i & 31);
  }
#pragma unroll
  for (int w = 0; w < 4; ++w)
    if (acc[w]) atomicOr(&m[(jl << 2) + w], acc[w]);
  __syncthreads();
  if (t < 64) colmask[((size_t)b * N + (g << 4)) * 4 + t] = m[t];
}

// ---------------------------------------------------------------------------
// K3: per-(b,c) update, one block each (1024 blocks, 256 threads).
//   passthrough: out = x + a (float4), then dims positions overwritten with
//   the closed-form x_new (masked sums; mask is usually empty).
// ---------------------------------------------------------------------------
__global__ __launch_bounds__(256) void k3_update(
    const float* __restrict__ x, const float* __restrict__ a,
    const float* __restrict__ ru, const int* __restrict__ dims,
    const float* __restrict__ vr2, const unsigned* __restrict__ colmask,
    float* __restrict__ out) {
  int bc = blockIdx.x;  // b*256 + c
  int b = bc >> 8;
  int t = threadIdx.x;
  __shared__ float xx[N];
  __shared__ float vv[N];
  __shared__ int dsh[N];

  const float* xrow = x + (size_t)bc * XD;
  const float* arow = a + (size_t)bc * XD;
  float* orow = out + (size_t)bc * XD;

  if (t < N) {
    int d = dims[t];
    dsh[t] = d;
    xx[t] = xrow[d];
    vv[t] = arow[d];  // vv = a * DT, DT = 1
  }

  // passthrough everywhere (float4), dims overwritten below after the barrier
  {
    const float4* x4 = (const float4*)xrow;
    const float4* a4 = (const float4*)arow;
    float4* o4 = (float4*)orow;
    float4 xv = x4[t], av = a4[t];
    o4[t] = make_float4(xv.x + av.x, xv.y + av.y, xv.z + av.z, xv.w + av.w);
  }
  __syncthreads();  // orders the float4 stores before the dims overwrite,
                    // and publishes xx/vv/dsh

  if (t < N) {
    int j = t;
    const unsigned* cm = colmask + ((size_t)b * N + j) * 4;
    unsigned mw0 = cm[0], mw1 = cm[1], mw2 = cm[2], mw3 = cm[3];
    float S = 0.f, sumV = 0.f, sumX = 0.f, R = 0.f;
    if (mw0 | mw1 | mw2 | mw3) {
      const float* vrb = vr2 + (size_t)b * N * N;
      const float* rub = ru + (size_t)bc * NP;
      unsigned mw[4] = {mw0, mw1, mw2, mw3};
      for (int w = 0; w < 4; ++w) {
        unsigned bits = mw[w];
        while (bits) {
          int i = (w << 5) + __ffs(bits) - 1;
          bits &= bits - 1;
          S += 1.f;
          sumV += vv[i];
          sumX += xx[i];
          float vr = sqrtf(vrb[i * N + j]);
          int p;
          float sgn;
          if (i < j) {
            p = i * N - ((i * (i + 1)) >> 1) + (j - i - 1);
            sgn = 1.f;
          } else {
            p = j * N - ((j * (j + 1)) >> 1) + (i - j - 1);
            sgn = -1.f;
          }
          R += sgn * TWO_PI_F * vr * rub[p];
        }
      }
    }
    float vj = vv[j];
    float v_new = vj + 0.5f * S * vj - 0.5f * sumV + R;
    float Dd = S + 1.f;
    float T = xx[j] + sumX;
    float x_new = 0.5f * xx[j] + 0.5f * T / Dd + 0.5f * v_new;
    orow[dsh[j]] = x_new;
  }
}

extern "C" void kernel_launch(void* const* d_in, const int* in_sizes, int n_in,
                              void* d_out, int out_size, void* d_ws, size_t ws_size,
                              hipStream_t stream) {
  const float* x = (const float*)d_in[0];
  // d_in[1] = v : unused by the reference computation
  const float* a = (const float*)d_in[2];
  const float* ru = (const float*)d_in[3];
  const int* dims = (const int*)d_in[4];
  float* out = (float*)d_out;

  float* xr2 = (float*)d_ws;                              // BS*N*N f32
  float* vr2 = xr2 + (size_t)BS * N * N;                  // BS*N*N f32
  float* pmax = vr2 + (size_t)BS * N * N;                 // BS*64 f32
  unsigned* colmask = (unsigned*)(pmax + (size_t)BS * 64);  // BS*N*4 u32

  k1_pairdist<<<dim3(8, 8, BS), 256, 0, stream>>>(x, a, dims, xr2, vr2, pmax);
  k2_mask<<<dim3(8, BS), 256, 0, stream>>>(xr2, vr2, pmax, colmask);
  k3_update<<<BS * CH, 256, 0, stream>>>(x, a, ru, dims, vr2, colmask, out);
}

// Round 3
// 20.138 us; speedup vs baseline: 2.7775x; 1.1177x over previous
//
#include <hip/hip_runtime.h>
#include <math.h>

#define BS 4
#define CH 256
#define XD 1024
#define N 128
#define NP 8128
#define TWO_PI_F 6.283185307179586f
#define PADW (CH + 4)  // LDS row stride in words: 260*4B = 1040 B, 16B-aligned; banks 4*row

// ---------------------------------------------------------------------------
// K1: per-batch pairwise squared distances over the channel axis, plus a
// per-block partial max of vr2 (for the v_r_max reduction).
//   xr2[b,i,j] = sum_c (x[b,c,dims[i]] - x[b,c,dims[j]])^2
//   vr2[b,i,j] = same with a (vv = a*DT, DT=1)
// Transposed LDS tiles [dim][channel] so the inner loop reads float4
// (ds_read_b128) instead of 4x ds_read_b32 -> VALU-bound, not LDS-bound.
// grid (8,8,4): 16x16 output tile per block, 256 threads.
// ---------------------------------------------------------------------------
__global__ __launch_bounds__(256) void k1_pairdist(
    const float* __restrict__ x, const float* __restrict__ a,
    const int* __restrict__ dims,
    float* __restrict__ xr2, float* __restrict__ vr2,
    float* __restrict__ pmax) {
  int ti = blockIdx.x, tj = blockIdx.y, b = blockIdx.z;
  int t = threadIdx.x;
  __shared__ float sXi[16][PADW];
  __shared__ float sXj[16][PADW];
  __shared__ float sAi[16][PADW];
  __shared__ float sAj[16][PADW];
  __shared__ float red[256];

  int lane16 = t & 15, grp = t >> 4;  // 16 dims x 16 channel-chunks
  int di = dims[ti * 16 + lane16];
  int dj = dims[tj * 16 + lane16];
  const float* xb = x + (size_t)b * CH * XD;
  const float* ab = a + (size_t)b * CH * XD;
  for (int c0 = 0; c0 < CH; c0 += 16) {
    int c = c0 + grp;
    sXi[lane16][c] = xb[c * XD + di];
    sXj[lane16][c] = xb[c * XD + dj];
    sAi[lane16][c] = ab[c * XD + di];
    sAj[lane16][c] = ab[c * XD + dj];
  }
  __syncthreads();

  int ii = t >> 4, jj = t & 15;  // consecutive t -> consecutive j (coalesced write)
  float accx = 0.f, accv = 0.f;
#pragma unroll 8
  for (int cq = 0; cq < CH / 4; ++cq) {
    float4 xi = *(const float4*)&sXi[ii][cq * 4];
    float4 xj = *(const float4*)&sXj[jj][cq * 4];
    float4 ai = *(const float4*)&sAi[ii][cq * 4];
    float4 aj = *(const float4*)&sAj[jj][cq * 4];
    float d0 = xi.x - xj.x;
    accx += d0 * d0;
    float d1 = xi.y - xj.y;
    accx += d1 * d1;
    float d2 = xi.z - xj.z;
    accx += d2 * d2;
    float d3 = xi.w - xj.w;
    accx += d3 * d3;
    float e0 = ai.x - aj.x;
    accv += e0 * e0;
    float e1 = ai.y - aj.y;
    accv += e1 * e1;
    float e2 = ai.z - aj.z;
    accv += e2 * e2;
    float e3 = ai.w - aj.w;
    accv += e3 * e3;
  }
  int i = ti * 16 + ii, j = tj * 16 + jj;
  xr2[((size_t)b * N + i) * N + j] = accx;
  vr2[((size_t)b * N + i) * N + j] = accv;

  // partial max of vr2 over this block's 256 elements
  red[t] = accv;
  __syncthreads();
  for (int s = 128; s > 0; s >>= 1) {
    if (t < s) red[t] = fmaxf(red[t], red[t + s]);
    __syncthreads();
  }
  if (t == 0) pmax[(b << 6) + tj * 8 + ti] = red[0];
}

// ---------------------------------------------------------------------------
// K2: finish the max reduction (64 partials per batch), then collision mask
// bits in a column-major bitmask.
//   mask[b,i,j] = (v_r/v_r_max * exp(-x_r)) > 0.5
//   colmask[b][j][w] bit (i&31) for i in [32w, 32w+32)
// grid (8, 4): block handles 16 columns of one batch, 256 threads.
// ---------------------------------------------------------------------------
__global__ __launch_bounds__(256) void k2_mask(
    const float* __restrict__ xr2, const float* __restrict__ vr2,
    const float* __restrict__ pmax, unsigned* __restrict__ colmask) {
  int g = blockIdx.x;  // column group: j in [16g, 16g+16)
  int b = blockIdx.y;
  int t = threadIdx.x;
  __shared__ float red[64];
  __shared__ unsigned m[16 * 4];
  if (t < 64) red[t] = pmax[(b << 6) + t];
  if (t < 64) m[t] = 0u;
  __syncthreads();
  float mx = 0.f;
#pragma unroll
  for (int k = 0; k < 64; ++k) mx = fmaxf(mx, red[k]);  // LDS broadcast, cheap
  float vrmax = sqrtf(mx);
  float inv = vrmax > 0.f ? 1.f / vrmax : 0.f;  // vrmax==0 -> all-false (matches nan>0.5)

  const float* vb = vr2 + (size_t)b * N * N;
  const float* xb = xr2 + (size_t)b * N * N;
  int jl = t & 15;  // local column
  int j = (g << 4) + jl;
  int i0 = t >> 4;  // 0..15
  unsigned acc[4] = {0u, 0u, 0u, 0u};
#pragma unroll
  for (int pass = 0; pass < 8; ++pass) {
    int i = (pass << 4) + i0;
    float vr = sqrtf(vb[i * N + j]);
    float ux = expf(-sqrtf(xb[i * N + j]));
    if (vr * inv * ux > 0.5f) acc[i >> 5] |= 1u << (i & 31);
  }
#pragma unroll
  for (int w = 0; w < 4; ++w)
    if (acc[w]) atomicOr(&m[(jl << 2) + w], acc[w]);
  __syncthreads();
  if (t < 64) colmask[((size_t)b * N + (g << 4)) * 4 + t] = m[t];
}

// ---------------------------------------------------------------------------
// K3: per-(b,c) update, one block each (1024 blocks, 256 threads).
//   passthrough: out = x + a (float4), then dims positions overwritten with
//   the closed-form x_new (masked sums; mask is usually empty).
// ---------------------------------------------------------------------------
__global__ __launch_bounds__(256) void k3_update(
    const float* __restrict__ x, const float* __restrict__ a,
    const float* __restrict__ ru, const int* __restrict__ dims,
    const float* __restrict__ vr2, const unsigned* __restrict__ colmask,
    float* __restrict__ out) {
  int bc = blockIdx.x;  // b*256 + c
  int b = bc >> 8;
  int t = threadIdx.x;
  __shared__ float xx[N];
  __shared__ float vv[N];
  __shared__ int dsh[N];

  const float* xrow = x + (size_t)bc * XD;
  const float* arow = a + (size_t)bc * XD;
  float* orow = out + (size_t)bc * XD;

  if (t < N) {
    int d = dims[t];
    dsh[t] = d;
    xx[t] = xrow[d];
    vv[t] = arow[d];  // vv = a * DT, DT = 1
  }

  // passthrough everywhere (float4), dims overwritten below after the barrier
  {
    const float4* x4 = (const float4*)xrow;
    const float4* a4 = (const float4*)arow;
    float4* o4 = (float4*)orow;
    float4 xv = x4[t], av = a4[t];
    o4[t] = make_float4(xv.x + av.x, xv.y + av.y, xv.z + av.z, xv.w + av.w);
  }
  __syncthreads();  // orders the float4 stores before the dims overwrite,
                    // and publishes xx/vv/dsh

  if (t < N) {
    int j = t;
    const unsigned* cm = colmask + ((size_t)b * N + j) * 4;
    unsigned mw0 = cm[0], mw1 = cm[1], mw2 = cm[2], mw3 = cm[3];
    float S = 0.f, sumV = 0.f, sumX = 0.f, R = 0.f;
    if (mw0 | mw1 | mw2 | mw3) {
      const float* vrb = vr2 + (size_t)b * N * N;
      const float* rub = ru + (size_t)bc * NP;
      unsigned mw[4] = {mw0, mw1, mw2, mw3};
      for (int w = 0; w < 4; ++w) {
        unsigned bits = mw[w];
        while (bits) {
          int i = (w << 5) + __ffs(bits) - 1;
          bits &= bits - 1;
          S += 1.f;
          sumV += vv[i];
          sumX += xx[i];
          float vr = sqrtf(vrb[i * N + j]);
          int p;
          float sgn;
          if (i < j) {
            p = i * N - ((i * (i + 1)) >> 1) + (j - i - 1);
            sgn = 1.f;
          } else {
            p = j * N - ((j * (j + 1)) >> 1) + (i - j - 1);
            sgn = -1.f;
          }
          R += sgn * TWO_PI_F * vr * rub[p];
        }
      }
    }
    float vj = vv[j];
    float v_new = vj + 0.5f * S * vj - 0.5f * sumV + R;
    float Dd = S + 1.f;
    float T = xx[j] + sumX;
    float x_new = 0.5f * xx[j] + 0.5f * T / Dd + 0.5f * v_new;
    orow[dsh[j]] = x_new;
  }
}

extern "C" void kernel_launch(void* const* d_in, const int* in_sizes, int n_in,
                              void* d_out, int out_size, void* d_ws, size_t ws_size,
                              hipStream_t stream) {
  const float* x = (const float*)d_in[0];
  // d_in[1] = v : unused by the reference computation
  const float* a = (const float*)d_in[2];
  const float* ru = (const float*)d_in[3];
  const int* dims = (const int*)d_in[4];
  float* out = (float*)d_out;

  float* xr2 = (float*)d_ws;                                // BS*N*N f32
  float* vr2 = xr2 + (size_t)BS * N * N;                    // BS*N*N f32
  float* pmax = vr2 + (size_t)BS * N * N;                   // BS*64 f32
  unsigned* colmask = (unsigned*)(pmax + (size_t)BS * 64);  // BS*N*4 u32

  k1_pairdist<<<dim3(8, 8, BS), 256, 0, stream>>>(x, a, dims, xr2, vr2, pmax);
  k2_mask<<<dim3(8, BS), 256, 0, stream>>>(xr2, vr2, pmax, colmask);
  k3_update<<<BS * CH, 256, 0, stream>>>(x, a, ru, dims, vr2, colmask, out);
}